// Round 5
// baseline (367.328 us; speedup 1.0000x reference)
//
#include <hip/hip_runtime.h>

#define DIMK 64
#define MC 256
#define RPW 16                          // rows per wave
#define NBLK (262144 / (RPW * 4))       // 4096 blocks of 4 waves

__global__ __launch_bounds__(256) __attribute__((amdgpu_waves_per_eu(4, 4)))
void fused_constrain_kernel(const float* __restrict__ z,
                            const float* __restrict__ pivot,
                            const float* __restrict__ At,
                            const float* __restrict__ b,
                            float* __restrict__ out) {
    const int tid  = threadIdx.x;
    const int lane = tid & 63;
    const int w    = tid >> 6;                       // wave id in block
    const int row0 = (blockIdx.x * 4 + w) * RPW;
    const float* __restrict__ zrow = z + row0 * DIMK;   // wave-uniform base

    // lane's 4 columns: At element [k*64 + lane] as float4 (16B, coalesced,
    // 64 lanes cover all 256 cols exactly once -> 1KB/row/wave, no dup)
    const float4* __restrict__ At4 = (const float4*)At + lane;

    float acc[RPW][4];
#pragma unroll
    for (int r = 0; r < RPW; ++r)
#pragma unroll
        for (int c = 0; c < 4; ++c) acc[r][c] = 0.f;

    float cv0 = 0.f, cv1 = 0.f, cv2 = 0.f, cv3 = 0.f;  // pivot @ At[:,cols]

#pragma unroll 1
    for (int kb = 0; kb < DIMK / 2; ++kb) {
        const int k0 = 2 * kb;
        // z chunk: 16 rows x 2 k's, wave-uniform address -> HW broadcast (L1)
        float2 zc[RPW];
#pragma unroll
        for (int r = 0; r < RPW; ++r)
            zc[r] = *(const float2*)(zrow + r * DIMK + k0);

        const float4 a0 = At4[k0 * 64];        // At row k0, 4 cols
        const float4 a1 = At4[(k0 + 1) * 64];  // At row k0+1

        const float p0 = pivot[k0], p1 = pivot[k0 + 1];  // uniform -> s_load
        cv0 = fmaf(p1, a1.x, fmaf(p0, a0.x, cv0));
        cv1 = fmaf(p1, a1.y, fmaf(p0, a0.y, cv1));
        cv2 = fmaf(p1, a1.z, fmaf(p0, a0.z, cv2));
        cv3 = fmaf(p1, a1.w, fmaf(p0, a0.w, cv3));

#pragma unroll
        for (int r = 0; r < RPW; ++r) {
            const float zx = zc[r].x, zy = zc[r].y;
            acc[r][0] = fmaf(zy, a1.x, fmaf(zx, a0.x, acc[r][0]));
            acc[r][1] = fmaf(zy, a1.y, fmaf(zx, a0.y, acc[r][1]));
            acc[r][2] = fmaf(zy, a1.z, fmaf(zx, a0.z, acc[r][2]));
            acc[r][3] = fmaf(zy, a1.w, fmaf(zx, a0.w, acc[r][3]));
        }
    }

    // ---- epilogue ----
    const float4 b4 = *(const float4*)(b + lane * 4);
    const float bv[4] = {b4.x, b4.y, b4.z, b4.w};
    const float cvv[4] = {cv0, cv1, cv2, cv3};
    const float pl = pivot[lane];                    // for the output rescale
    float* __restrict__ orow = out + row0 * DIMK;

#pragma unroll
    for (int r = 0; r < RPW; ++r) {
        float gm = 0.f;
#pragma unroll
        for (int c = 0; c < 4; ++c) {
            const float s  = acc[r][c];
            const float sa = s - bv[c];                      // sign_arg
            const float q  = fmaxf(s - cvv[c], 1e-9f);       // -clamped denom
            const float al = sa * __builtin_amdgcn_rcpf(q);
            gm = fmaxf(gm, (sa >= 0.f) ? al : 0.f);
        }
        // max over all 256 cols: 6-step butterfly across the full 64-lane wave
#pragma unroll
        for (int off = 1; off < 64; off <<= 1)
            gm = fmaxf(gm, __shfl_xor(gm, off));

        // out[row][lane] = z + gm*(pivot - z); z re-read coalesced (L1-hot)
        const float zi = zrow[r * DIMK + lane];
        orow[r * DIMK + lane] = fmaf(gm, pl - zi, zi);
    }
}

extern "C" void kernel_launch(void* const* d_in, const int* in_sizes, int n_in,
                              void* d_out, int out_size, void* d_ws, size_t ws_size,
                              hipStream_t stream) {
    const float* z     = (const float*)d_in[0];
    const float* pivot = (const float*)d_in[1];
    const float* At    = (const float*)d_in[2];
    const float* b     = (const float*)d_in[3];
    fused_constrain_kernel<<<dim3(NBLK), dim3(256), 0, stream>>>(
        z, pivot, At, b, (float*)d_out);
}